// Round 2
// baseline (164.681 us; speedup 1.0000x reference)
//
#include <hip/hip_runtime.h>

// Problem constants (fixed by the reference)
constexpr int B = 8, T = 128, S = 256, H = 512;
constexpr int TT = 2;  // t-rows per block in the fused attention kernel

#define DEVINL __device__ __forceinline__

// tanh(x) = 1 - 2/(exp2(2x*log2(e)) + 1); v_exp_f32 + v_rcp_f32, ~1e-6 abs err.
// Saturates correctly at +/-1 for large |x| (exp2->inf -> rcp->0; exp2->0 -> rcp(1)=1).
DEVINL float fast_tanh(float x) {
  float e = __builtin_amdgcn_exp2f(x * 2.8853900817779268f);  // 2*log2(e)
  return 1.0f - 2.0f * __builtin_amdgcn_rcpf(e + 1.0f);
}

// C[M,N] = act( A1 @ W1^T + A2 @ W2^T + bias ), all row-major, W stored [N,K].
// 64x64 tile, 256 threads, 4x4 micro-tile per thread (16x16 thread grid),
// BK=16, k-major LDS tiles so fragment reads are float4 (ds_read_b128).
__global__ __launch_bounds__(256) void gemm_tn_kernel(
    const float* __restrict__ A1, int lda1, const float* __restrict__ W1, int ldw1, int K1,
    const float* __restrict__ A2, int lda2, const float* __restrict__ W2, int ldw2, int K2,
    const float* __restrict__ bias, int act,
    float* __restrict__ C, int ldc) {
  __shared__ float As[16][68];  // [kk][row], pad to 68 floats
  __shared__ float Ws[16][68];  // [kk][col]
  const int tid = threadIdx.x;
  const int bm = blockIdx.x * 64;
  const int bn = blockIdx.y * 64;
  const int tr = tid >> 4;         // 0..15  (was the round-1 bug: had & 3)
  const int tc = tid & 15;         // 0..15
  const int lr = tid >> 2;         // 0..63 (row loaded by this thread)
  const int lc = (tid & 3) * 4;    // 0,4,8,12 (k-offset loaded)
  float acc[4][4] = {};

  for (int ph = 0; ph < 2; ++ph) {
    const float* A = ph ? A2 : A1;
    const float* W = ph ? W2 : W1;
    const int lda = ph ? lda2 : lda1;
    const int ldw = ph ? ldw2 : ldw1;
    const int K = ph ? K2 : K1;
    if (A == nullptr) continue;
    for (int k0 = 0; k0 < K; k0 += 16) {
      float4 av = *reinterpret_cast<const float4*>(&A[(size_t)(bm + lr) * lda + k0 + lc]);
      float4 wv = *reinterpret_cast<const float4*>(&W[(size_t)(bn + lr) * ldw + k0 + lc]);
      __syncthreads();  // previous tile fully consumed before overwrite
      As[lc + 0][lr] = av.x; As[lc + 1][lr] = av.y; As[lc + 2][lr] = av.z; As[lc + 3][lr] = av.w;
      Ws[lc + 0][lr] = wv.x; Ws[lc + 1][lr] = wv.y; Ws[lc + 2][lr] = wv.z; Ws[lc + 3][lr] = wv.w;
      __syncthreads();
#pragma unroll
      for (int kk = 0; kk < 16; ++kk) {
        float4 a4 = *reinterpret_cast<const float4*>(&As[kk][tr * 4]);
        float4 w4 = *reinterpret_cast<const float4*>(&Ws[kk][tc * 4]);
        float a[4] = {a4.x, a4.y, a4.z, a4.w};
        float w[4] = {w4.x, w4.y, w4.z, w4.w};
#pragma unroll
        for (int i = 0; i < 4; ++i)
#pragma unroll
          for (int j = 0; j < 4; ++j) acc[i][j] = fmaf(a[i], w[j], acc[i][j]);
      }
    }
  }

#pragma unroll
  for (int i = 0; i < 4; ++i) {
    const int row = bm + tr * 4 + i;
#pragma unroll
    for (int j = 0; j < 4; ++j) {
      const int col = bn + tc * 4 + j;
      float x = acc[i][j];
      if (bias) x += bias[col];
      if (act) x = fast_tanh(x);
      C[(size_t)row * ldc + col] = x;
    }
  }
}

// Fused: scores (v . tanh(qs+hs)) -> mask -> softmax over S -> context = attn @ enc.
// One block per (b, pair of t rows). 256 threads: thread s owns score column s.
__global__ __launch_bounds__(256) void attn_fused_kernel(
    const float* __restrict__ qs,   // (B*T, H)
    const float* __restrict__ hs,   // (B*S, H)
    const float* __restrict__ enc,  // (B*S, H)
    const float* __restrict__ v,    // (H)
    const int* __restrict__ lens,   // (B)
    float* __restrict__ ctx) {      // (B*T, H)
  __shared__ float s_qs[TT][H];
  __shared__ float s_v[H];
  __shared__ float s_attn[TT][S];
  const int tid = threadIdx.x;
  const int b = blockIdx.x / (T / TT);
  const int t0 = (blockIdx.x % (T / TT)) * TT;

  {  // stage qs rows (TT*H floats == 256 float4) and v
    const int idx = tid * 4;
    const int tt = idx >> 9;        // /H
    const int h = idx & (H - 1);
    *reinterpret_cast<float4*>(&s_qs[tt][h]) =
        *reinterpret_cast<const float4*>(&qs[(size_t)(b * T + t0 + tt) * H + h]);
    if (tid < H / 4)
      *reinterpret_cast<float4*>(&s_v[tid * 4]) =
          *reinterpret_cast<const float4*>(&v[tid * 4]);
  }
  __syncthreads();

  // ---- scores: thread s computes score[t0+tt][s] for tt in [0,TT) ----
  const int s = tid;
  float acc[TT] = {};
  const float4* hrow = reinterpret_cast<const float4*>(&hs[(size_t)(b * S + s) * H]);
#pragma unroll 4
  for (int h4 = 0; h4 < H / 4; ++h4) {
    const float4 hv = hrow[h4];
    const int h = h4 * 4;
#pragma unroll
    for (int tt = 0; tt < TT; ++tt) {
      acc[tt] += s_v[h + 0] * fast_tanh(s_qs[tt][h + 0] + hv.x);
      acc[tt] += s_v[h + 1] * fast_tanh(s_qs[tt][h + 1] + hv.y);
      acc[tt] += s_v[h + 2] * fast_tanh(s_qs[tt][h + 2] + hv.z);
      acc[tt] += s_v[h + 3] * fast_tanh(s_qs[tt][h + 3] + hv.w);
    }
  }
  const int len = lens[b];
#pragma unroll
  for (int tt = 0; tt < TT; ++tt) s_attn[tt][s] = (s < len) ? acc[tt] : -1e30f;
  __syncthreads();

  // ---- softmax: wave w reduces row w (TT waves active) ----
  if (tid < TT * 64) {
    const int w = tid >> 6, l = tid & 63;
    float vals[S / 64];
    float m = -1e30f;
#pragma unroll
    for (int i = 0; i < S / 64; ++i) {
      vals[i] = s_attn[w][l + 64 * i];
      m = fmaxf(m, vals[i]);
    }
#pragma unroll
    for (int off = 32; off > 0; off >>= 1) m = fmaxf(m, __shfl_xor(m, off));
    float sum = 0.f;
#pragma unroll
    for (int i = 0; i < S / 64; ++i) {
      vals[i] = __builtin_amdgcn_exp2f((vals[i] - m) * 1.4426950408889634f);
      sum += vals[i];
    }
#pragma unroll
    for (int off = 32; off > 0; off >>= 1) sum += __shfl_xor(sum, off);
    const float rs = __builtin_amdgcn_rcpf(sum);
#pragma unroll
    for (int i = 0; i < S / 64; ++i) s_attn[w][l + 64 * i] = vals[i] * rs;
  }
  __syncthreads();

  // ---- context: thread owns 2 h-columns; coalesced enc reads ----
  const int h0 = tid * 2;
  float c[TT][2] = {};
  for (int s2 = 0; s2 < S; ++s2) {
    const float2 ev = *reinterpret_cast<const float2*>(&enc[(size_t)(b * S + s2) * H + h0]);
#pragma unroll
    for (int tt = 0; tt < TT; ++tt) {
      const float a = s_attn[tt][s2];
      c[tt][0] = fmaf(a, ev.x, c[tt][0]);
      c[tt][1] = fmaf(a, ev.y, c[tt][1]);
    }
  }
#pragma unroll
  for (int tt = 0; tt < TT; ++tt) {
    *reinterpret_cast<float2*>(&ctx[(size_t)(b * T + t0 + tt) * H + h0]) =
        make_float2(c[tt][0], c[tt][1]);
  }
}

extern "C" void kernel_launch(void* const* d_in, const int* in_sizes, int n_in,
                              void* d_out, int out_size, void* d_ws, size_t ws_size,
                              hipStream_t stream) {
  const float* query = (const float*)d_in[0];  // (B,T,H)
  const float* enc = (const float*)d_in[1];    // (B,S,H)
  const int* lens = (const int*)d_in[2];       // (B)
  const float* W_s = (const float*)d_in[3];    // (H,H)
  const float* W_h = (const float*)d_in[4];    // (H,H)
  const float* v = (const float*)d_in[5];      // (H)
  const float* W_out = (const float*)d_in[6];  // (H,2H)
  const float* b_out = (const float*)d_in[7];  // (H)
  float* out = (float*)d_out;                  // (B,T,H)

  float* qs = (float*)d_ws;                  // B*T*H
  float* hs = qs + (size_t)B * T * H;        // B*S*H
  float* ctx = hs + (size_t)B * S * H;       // B*T*H

  dim3 blk(256);
  // qs = query @ W_s^T
  gemm_tn_kernel<<<dim3(B * T / 64, H / 64), blk, 0, stream>>>(
      query, H, W_s, H, H, nullptr, 0, nullptr, 0, 0, nullptr, 0, qs, H);
  // hs = enc @ W_h^T
  gemm_tn_kernel<<<dim3(B * S / 64, H / 64), blk, 0, stream>>>(
      enc, H, W_h, H, H, nullptr, 0, nullptr, 0, 0, nullptr, 0, hs, H);
  // scores -> softmax -> context
  attn_fused_kernel<<<dim3(B * T / TT), blk, 0, stream>>>(qs, hs, enc, v, lens, ctx);
  // out = tanh(ctx @ W_out[:, :H]^T + query @ W_out[:, H:]^T + b_out)
  gemm_tn_kernel<<<dim3(B * T / 64, H / 64), blk, 0, stream>>>(
      ctx, H, W_out, 2 * H, H, query, H, W_out + H, 2 * H, H, b_out, 1, out, H);
}

// Round 3
// 91.029 us; speedup vs baseline: 1.8091x; 1.8091x over previous
//
#include <hip/hip_runtime.h>

// Problem constants (fixed by the reference)
constexpr int B = 8, T = 128, S = 256, H = 512;

typedef __attribute__((ext_vector_type(4))) float f32x4;
typedef __attribute__((ext_vector_type(8))) short short8;
typedef __attribute__((ext_vector_type(4))) short short4v;

#define DEVINL __device__ __forceinline__

DEVINL float bf2f(short s) {
  union { unsigned u; float f; } x;
  x.u = ((unsigned)(unsigned short)s) << 16;
  return x.f;
}
// fp32 -> bf16 round-to-nearest-even (inputs are finite; no NaN path needed)
DEVINL short f2bf(float f) {
  unsigned u = __float_as_uint(f);
  unsigned r = (u + 0x7fffu + ((u >> 16) & 1u)) >> 16;
  return (short)r;
}
DEVINL float fast_tanh(float x) {
  float e = __builtin_amdgcn_exp2f(x * 2.8853900817779268f);  // 2*log2(e)
  return 1.0f - 2.0f * __builtin_amdgcn_rcpf(e + 1.0f);
}

// ---- workspace layout (bf16 elements from (short*)d_ws) ----
constexpr size_t N_QBF = (size_t)B * T * H;       // 524288
constexpr size_t N_EBF = (size_t)B * S * H;       // 1048576
constexpr size_t N_WSB = (size_t)H * H;           // 262144
constexpr size_t N_WHB = (size_t)H * H;           // 262144
constexpr size_t N_WOB = (size_t)H * 2 * H;       // 524288
constexpr size_t OFF_QBF = 0;
constexpr size_t OFF_EBF = OFF_QBF + N_QBF;
constexpr size_t OFF_WSB = OFF_EBF + N_EBF;
constexpr size_t OFF_WHB = OFF_WSB + N_WSB;
constexpr size_t OFF_WOB = OFF_WHB + N_WHB;
constexpr size_t OFF_QS  = OFF_WOB + N_WOB;       // qs bf16 (B*T*H)
constexpr size_t OFF_HS  = OFF_QS + N_QBF;        // hs bf16 (B*S*H)
constexpr size_t OFF_CTX = OFF_HS + N_EBF;        // ctx bf16 (B*T*H)
// total = 4,718,592 bf16 elems = 9 MiB of d_ws

// ---- fp32 -> bf16 conversion of the 5 read-only operands, one launch ----
// vec4 counts: q 131072 | e 262144 | Ws 65536 | Wh 65536 | Wo 131072 ; cum: 131072,393216,458752,524288,655360
__global__ __launch_bounds__(256) void convert_kernel(
    const float* __restrict__ q, const float* __restrict__ e,
    const float* __restrict__ ws, const float* __restrict__ wh,
    const float* __restrict__ wo, short* __restrict__ base) {
  int v = blockIdx.x * 256 + threadIdx.x;  // vec4 index
  if (v >= 655360) return;
  const float* src; short* dst; int local;
  if (v < 131072)      { src = q;  dst = base + OFF_QBF; local = v; }
  else if (v < 393216) { src = e;  dst = base + OFF_EBF; local = v - 131072; }
  else if (v < 458752) { src = ws; dst = base + OFF_WSB; local = v - 393216; }
  else if (v < 524288) { src = wh; dst = base + OFF_WHB; local = v - 458752; }
  else                 { src = wo; dst = base + OFF_WOB; local = v - 524288; }
  float4 f = reinterpret_cast<const float4*>(src)[local];
  short4v o;
  o.x = f2bf(f.x); o.y = f2bf(f.y); o.z = f2bf(f.z); o.w = f2bf(f.w);
  *reinterpret_cast<short4v*>(dst + (size_t)local * 4) = o;
}

// ---- MFMA GEMM core: 64x64 tile, 256 threads (4 waves, 2x2 wave grid),
//      BK=64 bf16, XOR-swizzled LDS (chunk ^= row&7 on 16B units).
//      C[m][n] = sum_k A[m][k] * Wt[n][k]  (Wt row-major [N][K]) ----
DEVINL void gemm_tile(const short* __restrict__ A, int lda,
                      const short* __restrict__ Wt, int ldw, int K,
                      int bm, int bn, short* As, short* Bs, f32x4 acc[2][2]) {
  const int tid = threadIdx.x;
  const int lane = tid & 63;
  const int wave = tid >> 6;
  const int wm = wave >> 1, wn = wave & 1;
  const int g = lane >> 4, r = lane & 15;
  for (int k0 = 0; k0 < K; k0 += 64) {
    __syncthreads();  // previous tile fully consumed
#pragma unroll
    for (int p = 0; p < 2; ++p) {
      const int idx = p * 256 + tid;
      const int row = idx >> 3, c = idx & 7;  // row 0..63, 16B-chunk 0..7
      short8 av = *reinterpret_cast<const short8*>(&A[(size_t)(bm + row) * lda + k0 + c * 8]);
      short8 wv = *reinterpret_cast<const short8*>(&Wt[(size_t)(bn + row) * ldw + k0 + c * 8]);
      *reinterpret_cast<short8*>(&As[row * 64 + ((c ^ (row & 7)) * 8)]) = av;
      *reinterpret_cast<short8*>(&Bs[row * 64 + ((c ^ (row & 7)) * 8)]) = wv;
    }
    __syncthreads();
#pragma unroll
    for (int kc = 0; kc < 2; ++kc) {
      short8 af[2], bfr[2];
#pragma unroll
      for (int mb = 0; mb < 2; ++mb) {
        const int ra = wm * 32 + mb * 16 + r;  // ra&7 == r&7
        af[mb] = *reinterpret_cast<const short8*>(&As[ra * 64 + (((kc * 4 + g) ^ (r & 7)) * 8)]);
      }
#pragma unroll
      for (int nb = 0; nb < 2; ++nb) {
        const int rb = wn * 32 + nb * 16 + r;
        bfr[nb] = *reinterpret_cast<const short8*>(&Bs[rb * 64 + (((kc * 4 + g) ^ (r & 7)) * 8)]);
      }
#pragma unroll
      for (int mb = 0; mb < 2; ++mb)
#pragma unroll
        for (int nb = 0; nb < 2; ++nb)
          acc[mb][nb] = __builtin_amdgcn_mfma_f32_16x16x32_bf16(af[mb], bfr[nb], acc[mb][nb], 0, 0, 0);
    }
  }
}

// qs = q_bf @ Ws^T (blocks 0..127), hs = e_bf @ Wh^T (blocks 128..383); bf16 out.
__global__ __launch_bounds__(256) void gemm_proj_kernel(
    const short* __restrict__ q_bf, const short* __restrict__ e_bf,
    const short* __restrict__ Wsb, const short* __restrict__ Whb,
    short* __restrict__ qs_bf, short* __restrict__ hs_bf) {
  __shared__ short As[64 * 64], Bs[64 * 64];
  f32x4 acc[2][2];
#pragma unroll
  for (int i = 0; i < 2; ++i)
#pragma unroll
    for (int j = 0; j < 2; ++j) acc[i][j] = (f32x4){0.f, 0.f, 0.f, 0.f};
  int bid = blockIdx.x;
  const short* A; const short* Wt; short* C;
  if (bid < 128) { A = q_bf; Wt = Wsb; C = qs_bf; }
  else           { bid -= 128; A = e_bf; Wt = Whb; C = hs_bf; }
  const int bm = (bid >> 3) * 64, bn = (bid & 7) * 64;
  gemm_tile(A, H, Wt, H, H, bm, bn, As, Bs, acc);
  const int lane = threadIdx.x & 63, wave = threadIdx.x >> 6;
  const int wm = wave >> 1, wn = wave & 1, g = lane >> 4, r = lane & 15;
#pragma unroll
  for (int mb = 0; mb < 2; ++mb)
#pragma unroll
    for (int nb = 0; nb < 2; ++nb)
#pragma unroll
      for (int i = 0; i < 4; ++i) {
        const int row = bm + wm * 32 + mb * 16 + g * 4 + i;
        const int col = bn + wn * 32 + nb * 16 + r;
        C[(size_t)row * H + col] = f2bf(acc[mb][nb][i]);
      }
}

// out = tanh([ctx|query] @ W_out^T + b_out), fp32 out. K = 512 + 512 phases.
__global__ __launch_bounds__(256) void gemm_out_kernel(
    const short* __restrict__ ctx_bf, const short* __restrict__ q_bf,
    const short* __restrict__ Wob, const float* __restrict__ bias,
    float* __restrict__ out) {
  __shared__ short As[64 * 64], Bs[64 * 64];
  f32x4 acc[2][2];
#pragma unroll
  for (int i = 0; i < 2; ++i)
#pragma unroll
    for (int j = 0; j < 2; ++j) acc[i][j] = (f32x4){0.f, 0.f, 0.f, 0.f};
  const int bm = (blockIdx.x >> 3) * 64, bn = (blockIdx.x & 7) * 64;
  gemm_tile(ctx_bf, H, Wob, 2 * H, H, bm, bn, As, Bs, acc);         // ctx @ W_out[:, :H]^T
  gemm_tile(q_bf, H, Wob + H, 2 * H, H, bm, bn, As, Bs, acc);       // + query @ W_out[:, H:]^T
  const int lane = threadIdx.x & 63, wave = threadIdx.x >> 6;
  const int wm = wave >> 1, wn = wave & 1, g = lane >> 4, r = lane & 15;
#pragma unroll
  for (int mb = 0; mb < 2; ++mb)
#pragma unroll
    for (int nb = 0; nb < 2; ++nb) {
      const int col = bn + wn * 32 + nb * 16 + r;
      const float bb = bias[col];
#pragma unroll
      for (int i = 0; i < 4; ++i) {
        const int row = bm + wm * 32 + mb * 16 + g * 4 + i;
        out[(size_t)row * H + col] = fast_tanh(acc[mb][nb][i] + bb);
      }
    }
}

// ---- fused scores+softmax+context. 512 threads (8 waves), block = (b, 2 t-rows).
// score'_s = -2 * sum_h v_h * rcp(1 + exp(2(q+h)))  [Σv const across s -> dropped:
// softmax shift-invariance]. qs pre-scaled by 2*log2e in LDS; exp2-domain throughout.
__global__ __launch_bounds__(512) void attn_kernel(
    const short* __restrict__ qs_bf, const short* __restrict__ hs_bf,
    const float* __restrict__ enc, const float* __restrict__ v,
    const int* __restrict__ lens, short* __restrict__ ctx_bf) {
  __shared__ float s_q[2][H];      // 2*log2e * qs row
  __shared__ float s_v[H];
  __shared__ float s_attn[2][S];
  const int tid = threadIdx.x;
  const int b = blockIdx.x >> 6;          // 64 blocks per batch (T/2)
  const int t0 = (blockIdx.x & 63) * 2;
  constexpr float C2 = 2.8853900817779268f;   // 2*log2(e)
  constexpr float L2E = 1.4426950408889634f;  // log2(e)

  if (tid < 128) {  // stage 2 qs rows, pre-scaled
    const int tt = tid >> 6, ch = tid & 63;
    short8 qv = *reinterpret_cast<const short8*>(&qs_bf[(size_t)(b * T + t0 + tt) * H + ch * 8]);
#pragma unroll
    for (int j = 0; j < 8; ++j) s_q[tt][ch * 8 + j] = C2 * bf2f(qv[j]);
  } else if (tid < 256) {  // stage v
    const int ch = tid - 128;
    reinterpret_cast<float4*>(s_v)[ch] = reinterpret_cast<const float4*>(v)[ch];
  }
  __syncthreads();

  // ---- scores: thread (tt, s) ----
  const int tt = tid >> 8, s = tid & 255;
  const short8* hrow = reinterpret_cast<const short8*>(&hs_bf[(size_t)(b * S + s) * H]);
  const float* qrow = s_q[tt];
  float acc0 = 0.f, acc1 = 0.f;
  for (int ch = 0; ch < H / 8; ++ch) {
    const short8 hv = hrow[ch];
    const int h = ch * 8;
#pragma unroll
    for (int j = 0; j < 8; j += 2) {
      float t0a = fmaf(C2, bf2f(hv[j]), qrow[h + j]);
      float t1a = fmaf(C2, bf2f(hv[j + 1]), qrow[h + j + 1]);
      float e0 = __builtin_amdgcn_exp2f(t0a);
      float e1 = __builtin_amdgcn_exp2f(t1a);
      float r0 = __builtin_amdgcn_rcpf(e0 + 1.0f);
      float r1 = __builtin_amdgcn_rcpf(e1 + 1.0f);
      acc0 = fmaf(s_v[h + j], r0, acc0);
      acc1 = fmaf(s_v[h + j + 1], r1, acc1);
    }
  }
  const int len = lens[b];
  s_attn[tt][s] = (s < len) ? (-2.0f * (acc0 + acc1)) : -1e30f;
  __syncthreads();

  // ---- softmax: wave 0 -> row 0, wave 1 -> row 1 ----
  if (tid < 128) {
    const int w = tid >> 6, l = tid & 63;
    float vals[S / 64];
    float m = -1e30f;
#pragma unroll
    for (int i = 0; i < S / 64; ++i) {
      vals[i] = s_attn[w][l + 64 * i];
      m = fmaxf(m, vals[i]);
    }
#pragma unroll
    for (int off = 32; off > 0; off >>= 1) m = fmaxf(m, __shfl_xor(m, off));
    float sum = 0.f;
#pragma unroll
    for (int i = 0; i < S / 64; ++i) {
      vals[i] = __builtin_amdgcn_exp2f((vals[i] - m) * L2E);
      sum += vals[i];
    }
#pragma unroll
    for (int off = 32; off > 0; off >>= 1) sum += __shfl_xor(sum, off);
    const float rs = __builtin_amdgcn_rcpf(sum);
#pragma unroll
    for (int i = 0; i < S / 64; ++i) s_attn[w][l + 64 * i] = vals[i] * rs;
  }
  __syncthreads();

  // ---- context: thread owns h-column tid; coalesced enc reads ----
  const int h0 = tid;
  const float* ecol = enc + (size_t)b * S * H + h0;
  float c0 = 0.f, c1 = 0.f;
  for (int ss = 0; ss < S; ++ss) {
    const float ev = ecol[(size_t)ss * H];
    c0 = fmaf(s_attn[0][ss], ev, c0);
    c1 = fmaf(s_attn[1][ss], ev, c1);
  }
  ctx_bf[(size_t)(b * T + t0) * H + h0] = f2bf(c0);
  ctx_bf[(size_t)(b * T + t0 + 1) * H + h0] = f2bf(c1);
}

extern "C" void kernel_launch(void* const* d_in, const int* in_sizes, int n_in,
                              void* d_out, int out_size, void* d_ws, size_t ws_size,
                              hipStream_t stream) {
  const float* query = (const float*)d_in[0];  // (B,T,H)
  const float* enc = (const float*)d_in[1];    // (B,S,H)
  const int* lens = (const int*)d_in[2];       // (B)
  const float* W_s = (const float*)d_in[3];    // (H,H)
  const float* W_h = (const float*)d_in[4];    // (H,H)
  const float* v = (const float*)d_in[5];      // (H)
  const float* W_out = (const float*)d_in[6];  // (H,2H)
  const float* b_out = (const float*)d_in[7];  // (H)
  float* out = (float*)d_out;                  // (B,T,H)

  short* wsb = (short*)d_ws;
  short* q_bf = wsb + OFF_QBF;
  short* e_bf = wsb + OFF_EBF;
  short* Wsb = wsb + OFF_WSB;
  short* Whb = wsb + OFF_WHB;
  short* Wob = wsb + OFF_WOB;
  short* qs_bf = wsb + OFF_QS;
  short* hs_bf = wsb + OFF_HS;
  short* ctx_bf = wsb + OFF_CTX;

  convert_kernel<<<2560, 256, 0, stream>>>(query, enc, W_s, W_h, W_out, wsb);
  gemm_proj_kernel<<<384, 256, 0, stream>>>(q_bf, e_bf, Wsb, Whb, qs_bf, hs_bf);
  attn_kernel<<<B * T / 2, 512, 0, stream>>>(qs_bf, hs_bf, enc, v, lens, ctx_bf);
  gemm_out_kernel<<<128, 256, 0, stream>>>(ctx_bf, q_bf, Wob, b_out, out);
}